// Round 8
// baseline (291.505 us; speedup 1.0000x reference)
//
#include <hip/hip_runtime.h>
#include <hip/hip_bf16.h>
#include <float.h>
#include <math.h>

#define BB 64
#define NNtok 197
#define DD 768
#define HH 12
#define PP 12
#define CC 200
#define NPATCH 196

#define FSEL 0
#define FCAST 64
#define FMID 128
#define FHEAD 192

typedef short bf16x8 __attribute__((ext_vector_type(8)));
typedef float f32x4 __attribute__((ext_vector_type(4)));

__device__ __forceinline__ unsigned short bf16_bits(float x) {
  __hip_bfloat16 h = __float2bfloat16(x);
  return *reinterpret_cast<unsigned short*>(&h);
}
__device__ __forceinline__ float u2f(unsigned int u) {
  union { unsigned int u; float f; } cv; cv.u = u; return cv.f;
}
__device__ __forceinline__ float bfu(unsigned short us) {
  union { unsigned int u; float f; } cv; cv.u = ((unsigned int)us) << 16; return cv.f;
}

__device__ __forceinline__ void waitflag(int* p, int target) {
  int spin = 0;
  while (__hip_atomic_load(p, __ATOMIC_ACQUIRE, __HIP_MEMORY_SCOPE_AGENT) < target) {
    if (++spin > (1 << 22)) break;  // bounded: fail-wrong, never hang
    __builtin_amdgcn_s_sleep(2);
  }
}
__device__ __forceinline__ void sigflag(int* p) {
  __threadfence();
  __hip_atomic_fetch_add(p, 1, __ATOMIC_RELEASE, __HIP_MEMORY_SCOPE_AGENT);
}

__global__ void k_reset(int* flags) { flags[threadIdx.x] = 0; }

__global__ __launch_bounds__(256) void k_mega(
    const float* __restrict__ hidden, const float* __restrict__ attns,
    const int* __restrict__ labels, const float* __restrict__ ln1_g,
    const float* __restrict__ ln1_b, const float* __restrict__ w_in,
    const float* __restrict__ b_in, const float* __restrict__ w_out,
    const float* __restrict__ b_out, const float* __restrict__ ln2_g,
    const float* __restrict__ ln2_b, const float* __restrict__ w_pool,
    const float* __restrict__ b_pool, const float* __restrict__ ptemp,
    const float* __restrict__ w_mlp, const float* __restrict__ b_mlp,
    const float* __restrict__ arc_w, float* __restrict__ out,
    float* __restrict__ part_ws, float* __restrict__ pmlp,
    __hip_bfloat16* __restrict__ parts_bf, __hip_bfloat16* __restrict__ w_in_bf,
    __hip_bfloat16* __restrict__ w_out_bf, __hip_bfloat16* __restrict__ w_mlp_bf,
    int* __restrict__ flags) {
  __shared__ __align__(16) char sm[43136];
  int t = threadIdx.x, blk = blockIdx.x;
  int wv = t >> 6, ln = t & 63;

  // ================= P0: select+top12+LN1 (blk<64) | weight casts ===========
  if (blk < 64) {
    int b = blk;
    float* sc = (float*)sm;
    int* sel_s = (int*)(sm + 1024);
    float acc = -FLT_MAX;
    if (t < NPATCH) {
      acc = 0.f;
#pragma unroll
      for (int l = 0; l < 4; l++) {
        float part = 0.f;
#pragma unroll
        for (int h = 0; h < HH; h++) {
          size_t base = (size_t)((l * BB + b) * HH + h) * ((size_t)NNtok * NNtok);
          part += attns[base + 1 + t];
        }
        acc += part * (1.f / 12.f);
      }
      acc *= 0.25f;
    }
    sc[t] = acc;
    __syncthreads();
    if (t < 64) {
      float v[4]; int idx[4];
#pragma unroll
      for (int j = 0; j < 4; j++) { idx[j] = t + j * 64; v[j] = sc[idx[j]]; }
      for (int it = 0; it < PP; ++it) {
        float bv = v[0]; int bidx = idx[0];
#pragma unroll
        for (int j = 1; j < 4; j++)
          if (v[j] > bv || (v[j] == bv && idx[j] < bidx)) { bv = v[j]; bidx = idx[j]; }
        float cv = bv; int ci = bidx;
#pragma unroll
        for (int off = 32; off > 0; off >>= 1) {
          float ov = __shfl_xor(cv, off); int oi = __shfl_xor(ci, off);
          if (ov > cv || (ov == cv && oi < ci)) { cv = ov; ci = oi; }
        }
        if (t == 0) sel_s[it] = ci;
#pragma unroll
        for (int j = 0; j < 4; j++)
          if (idx[j] == ci) v[j] = -FLT_MAX;
      }
    }
    __syncthreads();
#pragma unroll
    for (int q = 0; q < 3; q++) {
      int i = wv * 3 + q;
      const float* row = hidden + ((size_t)b * NNtok + 1 + sel_s[i]) * DD;
      float x[12], s1 = 0.f, s2 = 0.f;
#pragma unroll
      for (int k = 0; k < 12; k++) {
        x[k] = row[ln + 64 * k];
        s1 += x[k]; s2 += x[k] * x[k];
      }
#pragma unroll
      for (int off = 32; off > 0; off >>= 1) {
        s1 += __shfl_xor(s1, off); s2 += __shfl_xor(s2, off);
      }
      float m = s1 * (1.f / DD);
      float rstd = rsqrtf(s2 * (1.f / DD) - m * m + 1e-5f);
      __hip_bfloat16* outp_ = parts_bf + ((size_t)b * PP + i) * DD;
#pragma unroll
      for (int k = 0; k < 12; k++) {
        int d = ln + 64 * k;
        outp_[d] = __float2bfloat16((x[k] - m) * rstd * ln1_g[d] + ln1_b[d]);
      }
    }
    __syncthreads();
    if (t == 0) sigflag(&flags[FSEL + b]);
  } else {
    for (int i = (blk - 64) * 256 + t; i < 737280; i += 192 * 256) {
      const float* src; __hip_bfloat16* dst; int off;
      if (i < 442368) { src = w_in; dst = w_in_bf; off = i; }
      else if (i < 589824) { src = w_out; dst = w_out_bf; off = i - 442368; }
      else { src = w_mlp; dst = w_mlp_bf; off = i - 589824; }
      float4 v = ((const float4*)src)[off];
      union { unsigned short u[4]; ushort4 v4; } p;
      p.u[0] = bf16_bits(v.x); p.u[1] = bf16_bits(v.y);
      p.u[2] = bf16_bits(v.z); p.u[3] = bf16_bits(v.w);
      ((ushort4*)dst)[off] = p.v4;
    }
    __syncthreads();
    if (t == 0) sigflag(&flags[FCAST]);
  }

  // ================= P1: per (b,hg) qkv GEMM + attn + partial wout ==========
  {
    int b = ((blk >> 3) << 1) | (blk & 1);  // XCD-affine: hg pinned to XCD pair
    int hg = (blk >> 1) & 3;
    if (t == 0) {
      waitflag(&flags[FSEL + b], 1);
      waitflag(&flags[FCAST], 192);
    }
    __syncthreads();
    int wave = wv, lane = t & 63, lr = lane & 15, kg = lane >> 4;
    unsigned short (*qkv3)[16][192] = (unsigned short (*)[16][192])sm;
    unsigned short (*o3)[192] = (unsigned short (*)[192])(sm + 18432);
    float* scores = (float*)(sm + 24576);

    int pr = lr < 12 ? lr : 11;
    const __hip_bfloat16* Ab = parts_bf + ((size_t)b * 12 + pr) * DD + kg * 8;
    int wrow[9];
#pragma unroll
    for (int nf = 0; nf < 9; nf++) {
      int lc = wave * 144 + nf * 16 + lr;
      int s = lc / 192, d2 = lc - s * 192;
      wrow[nf] = s * 768 + hg * 192 + d2;
    }
    f32x4 acc[9];
#pragma unroll
    for (int nf = 0; nf < 9; nf++) { acc[nf][0]=0.f; acc[nf][1]=0.f; acc[nf][2]=0.f; acc[nf][3]=0.f; }
    for (int k0 = 0; k0 < 768; k0 += 32) {
      bf16x8 af = *(const bf16x8*)(Ab + k0);
      bf16x8 wf[9];
#pragma unroll
      for (int nf = 0; nf < 9; nf++)
        wf[nf] = *(const bf16x8*)(w_in_bf + (size_t)wrow[nf] * DD + kg * 8 + k0);
#pragma unroll
      for (int nf = 0; nf < 9; nf++)
        acc[nf] = __builtin_amdgcn_mfma_f32_16x16x32_bf16(af, wf[nf], acc[nf], 0, 0, 0);
    }
#pragma unroll
    for (int nf = 0; nf < 9; nf++) {
      int lc = wave * 144 + nf * 16 + lr;
      int s = lc / 192, d2 = lc - s * 192;
      float bv = b_in[s * 768 + hg * 192 + d2];
#pragma unroll
      for (int r = 0; r < 4; r++) {
        int p = kg * 4 + r;
        qkv3[s][p][d2] = bf16_bits(acc[nf][r] + bv);
      }
    }
    __syncthreads();
    for (int e = t; e < 432; e += 256) {
      int h = e / 144, rem = e - h * 144;
      int i = rem / 12, j = rem - i * 12;
      float s = 0.f;
#pragma unroll
      for (int d = 0; d < 64; d++)
        s += bfu(qkv3[0][i][h * 64 + d]) * bfu(qkv3[1][j][h * 64 + d]);
      scores[e] = s * 0.125f;
    }
    __syncthreads();
    if (t < 36) {
      int h = t / 12, i = t - h * 12;
      float* row = scores + h * 144 + i * 12;
      float m = -FLT_MAX;
#pragma unroll
      for (int j = 0; j < 12; j++) m = fmaxf(m, row[j]);
      float e2[12], sum = 0.f;
#pragma unroll
      for (int j = 0; j < 12; j++) { e2[j] = expf(row[j] - m); sum += e2[j]; }
      float inv = 1.f / sum;
#pragma unroll
      for (int j = 0; j < 12; j++) row[j] = e2[j] * inv;
    }
    __syncthreads();
    for (int o = t; o < 2304; o += 256) {
      int i = o / 192, d2 = o - i * 192;
      int h = d2 >> 6;
      float s = 0.f;
#pragma unroll
      for (int j = 0; j < 12; j++)
        s += scores[h * 144 + i * 12 + j] * bfu(qkv3[2][j][d2]);
      o3[i][d2] = bf16_bits(s);
    }
    __syncthreads();
    f32x4 acc2[12];
#pragma unroll
    for (int jf = 0; jf < 12; jf++) { acc2[jf][0]=0.f; acc2[jf][1]=0.f; acc2[jf][2]=0.f; acc2[jf][3]=0.f; }
    const unsigned short* Ob = &o3[0][0] + lr * 192 + kg * 8;
    for (int k0 = 0; k0 < 192; k0 += 32) {
      bf16x8 af = *(const bf16x8*)(Ob + k0);
      bf16x8 wf[12];
#pragma unroll
      for (int jf = 0; jf < 12; jf++) {
        int j = wave * 192 + jf * 16 + lr;
        wf[jf] = *(const bf16x8*)(w_out_bf + (size_t)j * DD + hg * 192 + kg * 8 + k0);
      }
#pragma unroll
      for (int jf = 0; jf < 12; jf++)
        acc2[jf] = __builtin_amdgcn_mfma_f32_16x16x32_bf16(af, wf[jf], acc2[jf], 0, 0, 0);
    }
#pragma unroll
    for (int jf = 0; jf < 12; jf++) {
      int j = wave * 192 + jf * 16 + lr;
#pragma unroll
      for (int r = 0; r < 4; r++) {
        int p = kg * 4 + r;
        if (p < 12)
          part_ws[(((size_t)b * 4 + hg) * 12 + p) * DD + j] = acc2[jf][r];
      }
    }
    __syncthreads();
    if (t == 0) sigflag(&flags[FMID + b]);
  }

  // ================= P2: per-b reduce + LN2 + pool + full MLP ===============
  if (blk < 64) {
    int b = blk;
    if (t == 0) waitflag(&flags[FMID + b], 4);
    __syncthreads();
    float* a12 = (float*)sm;                 // 12*768
    float* raww_s = (float*)(sm + 36864);    // 12
    float* pfeat = (float*)(sm + 36912);     // 768
    for (int u = t; u < 9216; u += 256) {
      int j = u % 768;
      float s = b_out[j];
#pragma unroll
      for (int hg = 0; hg < 4; hg++)
        s += part_ws[(((size_t)b * 4 + hg) * 12) * DD + u];
      a12[u] = s;
    }
    __syncthreads();
#pragma unroll
    for (int q = 0; q < 3; q++) {
      int r = wv * 3 + q;
      float x[12], s1 = 0.f, s2 = 0.f;
#pragma unroll
      for (int k = 0; k < 12; k++) {
        x[k] = a12[r * 768 + ln + 64 * k];
        s1 += x[k]; s2 += x[k] * x[k];
      }
#pragma unroll
      for (int off = 32; off > 0; off >>= 1) {
        s1 += __shfl_xor(s1, off); s2 += __shfl_xor(s2, off);
      }
      float m = s1 * (1.f / DD);
      float rstd = rsqrtf(s2 * (1.f / DD) - m * m + 1e-5f);
      float pl = 0.f;
#pragma unroll
      for (int k = 0; k < 12; k++) {
        int d = ln + 64 * k;
        float y = (x[k] - m) * rstd * ln2_g[d] + ln2_b[d];
        a12[r * 768 + d] = y;
        pl += y * w_pool[d];
      }
#pragma unroll
      for (int off = 32; off > 0; off >>= 1) pl += __shfl_xor(pl, off);
      if (ln == 0) raww_s[r] = pl + b_pool[0];
    }
    __syncthreads();
    float wts[12];
    {
      float inv = 1.f / fmaxf(ptemp[0], 0.3f);
      float z[12], mx = -FLT_MAX;
#pragma unroll
      for (int p = 0; p < 12; p++) { z[p] = raww_s[p] * inv; mx = fmaxf(mx, z[p]); }
      float s = 0.f;
#pragma unroll
      for (int p = 0; p < 12; p++) { z[p] = expf(z[p] - mx); s += z[p]; }
      float is = 1.f / s;
#pragma unroll
      for (int p = 0; p < 12; p++) wts[p] = z[p] * is;
    }
    for (int d = t; d < 768; d += 256) {
      float s = 0.f;
#pragma unroll
      for (int p = 0; p < 12; p++) s += a12[p * 768 + d] * wts[p];
      pfeat[d] = s;
    }
    __syncthreads();
#pragma unroll
    for (int r3 = 0; r3 < 3; r3++) {
      int j = t + 256 * r3;
      const uint4* wr = (const uint4*)(w_mlp_bf + (size_t)j * DD);
      float acc2 = b_mlp[j];
      for (int k = 0; k < 96; k++) {
        uint4 w4 = wr[k];
        const float* pf = &pfeat[k * 8];
        acc2 += pf[0] * u2f(w4.x << 16) + pf[1] * u2f(w4.x & 0xFFFF0000u)
              + pf[2] * u2f(w4.y << 16) + pf[3] * u2f(w4.y & 0xFFFF0000u)
              + pf[4] * u2f(w4.z << 16) + pf[5] * u2f(w4.z & 0xFFFF0000u)
              + pf[6] * u2f(w4.w << 16) + pf[7] * u2f(w4.w & 0xFFFF0000u);
      }
      pmlp[(size_t)b * DD + j] = fmaxf(acc2, 0.f);
    }
    __syncthreads();
    if (t == 0) sigflag(&flags[FHEAD + b]);
  }

  // ================= P3: fusion + ArcFace (4 blocks per b, 50 classes) ======
  {
    int b = blk & 63, q3 = blk >> 6;
    if (t == 0) waitflag(&flags[FHEAD + b], 1);
    __syncthreads();
    float4* fs4 = (float4*)sm;
    float* a4 = (float*)(sm + 6144);
    const float4* cls4 = (const float4*)(hidden + (size_t)b * NNtok * DD);
    const float4* pm4 = (const float4*)(pmlp + (size_t)b * DD);
    for (int u = t; u < 384; u += 256) fs4[u] = (u < 192) ? cls4[u] : pm4[u - 192];
    __syncthreads();
    float s = 0.f;
    for (int u = t; u < 384; u += 256) {
      float4 v = fs4[u];
      s += v.x * v.x + v.y * v.y + v.z * v.z + v.w * v.w;
    }
#pragma unroll
    for (int off = 32; off > 0; off >>= 1) s += __shfl_xor(s, off);
    if (ln == 0) a4[wv] = s;
    __syncthreads();
    float rnf = rsqrtf(a4[0] + a4[1] + a4[2] + a4[3]);
    int lab = labels[b];
    const float cos_m = 0.8775825618903728f, sin_m = 0.479425538604203f;
    const float th = -0.8775825618903728f, mm = 0.2397127693021015f;
    int c0 = q3 * 50;
    for (int ci = 0;; ci++) {
      int c = c0 + wv + 4 * ci;
      if (c >= c0 + 50) break;
      const float4* wr = (const float4*)(arc_w + (size_t)c * 1536);
      float acc = 0.f, nw = 0.f;
#pragma unroll
      for (int k = 0; k < 6; k++) {
        float4 a = fs4[ln + 64 * k];
        float4 w = wr[ln + 64 * k];
        acc += a.x * w.x + a.y * w.y + a.z * w.z + a.w * w.w;
        nw += w.x * w.x + w.y * w.y + w.z * w.z + w.w * w.w;
      }
#pragma unroll
      for (int off = 32; off > 0; off >>= 1) {
        acc += __shfl_xor(acc, off); nw += __shfl_xor(nw, off);
      }
      if (ln == 0) {
        float cosv = acc * rsqrtf(nw) * rnf;
        float s2 = 1.f - cosv * cosv;
        s2 = fminf(fmaxf(s2, 0.f), 1.f);
        float sinv = sqrtf(s2);
        float phi = cosv * cos_m - sinv * sin_m;
        phi = (cosv > th) ? phi : (cosv - mm);
        out[(size_t)b * CC + c] = ((c == lab) ? phi : cosv) * 30.f;
      }
    }
  }
}

extern "C" void kernel_launch(void* const* d_in, const int* in_sizes, int n_in,
                              void* d_out, int out_size, void* d_ws, size_t ws_size,
                              hipStream_t stream) {
  const float* hidden = (const float*)d_in[0];
  const float* attns  = (const float*)d_in[1];
  const int*   labels = (const int*)d_in[2];
  const float* ln1_g  = (const float*)d_in[3];
  const float* ln1_b  = (const float*)d_in[4];
  const float* w_in   = (const float*)d_in[5];
  const float* b_in   = (const float*)d_in[6];
  const float* w_out  = (const float*)d_in[7];
  const float* b_out  = (const float*)d_in[8];
  const float* ln2_g  = (const float*)d_in[9];
  const float* ln2_b  = (const float*)d_in[10];
  const float* w_pool = (const float*)d_in[11];
  const float* b_pool = (const float*)d_in[12];
  const float* ptemp  = (const float*)d_in[13];
  const float* w_mlp  = (const float*)d_in[14];
  const float* b_mlp  = (const float*)d_in[15];
  const float* arc_w  = (const float*)d_in[16];
  float* outp = (float*)d_out;

  float* F = (float*)d_ws;
  float* part_ws = F;                                          // 2359296 f32
  float* pmlp    = F + 2359296;                                // 49152
  __hip_bfloat16* parts_bf = (__hip_bfloat16*)(F + 2408448);   // 589824 bf16
  __hip_bfloat16* w_in_bf  = (__hip_bfloat16*)(F + 2703360);   // 1769472 bf16
  __hip_bfloat16* w_out_bf = (__hip_bfloat16*)(F + 3588096);   // 589824 bf16
  __hip_bfloat16* w_mlp_bf = (__hip_bfloat16*)(F + 3883008);   // 589824 bf16
  int* flags = (int*)(F + 4177920);                            // 256 ints

  k_reset<<<1, 256, 0, stream>>>(flags);
  k_mega<<<256, 256, 0, stream>>>(hidden, attns, labels, ln1_g, ln1_b, w_in,
                                  b_in, w_out, b_out, ln2_g, ln2_b, w_pool,
                                  b_pool, ptemp, w_mlp, b_mlp, arc_w, outp,
                                  part_ws, pmlp, parts_bf, w_in_bf, w_out_bf,
                                  w_mlp_bf, flags);
}

// Round 9
// 205.857 us; speedup vs baseline: 1.4161x; 1.4161x over previous
//
#include <hip/hip_runtime.h>
#include <hip/hip_bf16.h>
#include <float.h>
#include <math.h>

#define BB 64
#define NNtok 197
#define DD 768
#define HH 12
#define PP 12
#define CC 200
#define NPATCH 196
#define QSTR 2312  // qkv LDS row stride (bf16 elems), padded vs 2304

typedef short bf16x8 __attribute__((ext_vector_type(8)));
typedef short bf16x4 __attribute__((ext_vector_type(4)));
typedef float f32x4 __attribute__((ext_vector_type(4)));

__device__ __forceinline__ unsigned short bf16_bits(float x) {
  __hip_bfloat16 h = __float2bfloat16(x);
  return *reinterpret_cast<unsigned short*>(&h);
}
__device__ __forceinline__ float u2f(unsigned int u) {
  union { unsigned int u; float f; } cv; cv.u = u; return cv.f;
}
__device__ __forceinline__ float bfu(unsigned short us) {
  union { unsigned int u; float f; } cv; cv.u = ((unsigned int)us) << 16; return cv.f;
}

// ============ K1: cast w_in, w_out, w_mlp to bf16 ===========================
__global__ __launch_bounds__(256) void k1_cast(
    const float* __restrict__ w1, const float* __restrict__ w2,
    const float* __restrict__ w3, __hip_bfloat16* __restrict__ o1,
    __hip_bfloat16* __restrict__ o2, __hip_bfloat16* __restrict__ o3) {
  for (int i = blockIdx.x * 256 + threadIdx.x; i < 737280; i += 256 * 256) {
    const float* src; __hip_bfloat16* dst; int off;
    if (i < 442368) { src = w1; dst = o1; off = i; }
    else if (i < 589824) { src = w2; dst = o2; off = i - 442368; }
    else { src = w3; dst = o3; off = i - 589824; }
    float4 v = ((const float4*)src)[off];
    union { unsigned short u[4]; ushort4 v4; } p;
    p.u[0] = bf16_bits(v.x); p.u[1] = bf16_bits(v.y);
    p.u[2] = bf16_bits(v.z); p.u[3] = bf16_bits(v.w);
    ((ushort4*)dst)[off] = p.v4;
  }
}

// ============ K2: one block per batch; full per-b pipeline ==================
// LDS map (bytes): A=[0,18432) parts/o3 (swizzled bf16 [12][768])
//                  B=[18432,73920) qkv [12][QSTR] bf16 -> aout/pfeat/fs/misc
//                  C=[73920,80832) scores f32 [12][144]
__global__ __launch_bounds__(1024, 4) void k2_all(
    const float* __restrict__ hidden, const float* __restrict__ attns,
    const int* __restrict__ labels, const float* __restrict__ ln1_g,
    const float* __restrict__ ln1_b, const __hip_bfloat16* __restrict__ w_in_bf,
    const float* __restrict__ b_in, const __hip_bfloat16* __restrict__ w_out_bf,
    const float* __restrict__ b_out, const float* __restrict__ ln2_g,
    const float* __restrict__ ln2_b, const float* __restrict__ w_pool,
    const float* __restrict__ b_pool, const float* __restrict__ ptemp,
    const __hip_bfloat16* __restrict__ w_mlp_bf, const float* __restrict__ b_mlp,
    const float* __restrict__ arc_w, float* __restrict__ out) {
  __shared__ __align__(16) char sm[80832];
  int t = threadIdx.x, b = blockIdx.x;
  int wv = t >> 6, ln = t & 63;
  char* A = sm;
  char* Bz = sm + 18432;
  float* scoresC = (float*)(sm + 73920);

  // ---------------- Phase S: scores + top-12 + gather + LN1 ----------------
  {
    float* sgrp = (float*)Bz;           // 4 x 256 f32
    float* sc = (float*)(Bz + 4096);    // 256 f32
    int* sel = (int*)(Bz + 5120);       // 12 int
    int g = t >> 8, p = t & 255;
    if (p < NPATCH) {
      float part = 0.f;
#pragma unroll
      for (int h = 0; h < HH; h++) {
        size_t base = (size_t)((g * BB + b) * HH + h) * ((size_t)NNtok * NNtok);
        part += attns[base + 1 + p];
      }
      sgrp[g * 256 + p] = part;
    }
    __syncthreads();
    if (t < 256) {
      float acc = -FLT_MAX;
      if (t < NPATCH)
        acc = (sgrp[t] * (1.f / 12.f) + sgrp[256 + t] * (1.f / 12.f) +
               sgrp[512 + t] * (1.f / 12.f) + sgrp[768 + t] * (1.f / 12.f)) * 0.25f;
      sc[t] = acc;
    }
    __syncthreads();
    if (t < 64) {
      float v[4]; int idx[4];
#pragma unroll
      for (int j = 0; j < 4; j++) { idx[j] = t + j * 64; v[j] = sc[idx[j]]; }
      for (int it = 0; it < PP; ++it) {
        float bv = v[0]; int bidx = idx[0];
#pragma unroll
        for (int j = 1; j < 4; j++)
          if (v[j] > bv || (v[j] == bv && idx[j] < bidx)) { bv = v[j]; bidx = idx[j]; }
        float cv = bv; int ci = bidx;
#pragma unroll
        for (int off = 32; off > 0; off >>= 1) {
          float ov = __shfl_xor(cv, off); int oi = __shfl_xor(ci, off);
          if (ov > cv || (ov == cv && oi < ci)) { cv = ov; ci = oi; }
        }
        if (t == 0) sel[it] = ci;
#pragma unroll
        for (int j = 0; j < 4; j++)
          if (idx[j] == ci) v[j] = -FLT_MAX;
      }
    }
    __syncthreads();
    if (wv < 12) {
      int i = wv;
      const float* row = hidden + ((size_t)b * NNtok + 1 + sel[i]) * DD;
      float x[12], s1 = 0.f, s2 = 0.f;
#pragma unroll
      for (int k = 0; k < 12; k++) {
        x[k] = row[ln + 64 * k];
        s1 += x[k]; s2 += x[k] * x[k];
      }
#pragma unroll
      for (int off = 32; off > 0; off >>= 1) {
        s1 += __shfl_xor(s1, off); s2 += __shfl_xor(s2, off);
      }
      float m = s1 * (1.f / DD);
      float rstd = rsqrtf(s2 * (1.f / DD) - m * m + 1e-5f);
      int sw = (i & 7) << 4;
#pragma unroll
      for (int k = 0; k < 12; k++) {
        int d = ln + 64 * k;
        *(unsigned short*)(A + i * 1536 + ((2 * d) ^ sw)) =
            bf16_bits((x[k] - m) * rstd * ln1_g[d] + ln1_b[d]);
      }
    }
  }
  __syncthreads();

  // ---------------- Phase G1: qkv = parts @ w_in^T + b_in (LDS out) --------
  {
    int lr = ln & 15, kg = ln >> 4;
    int pr = lr < 12 ? lr : 11;
    int asw = (pr & 7) << 4;
    f32x4 acc[9];
#pragma unroll
    for (int nf = 0; nf < 9; nf++) { acc[nf][0]=0.f; acc[nf][1]=0.f; acc[nf][2]=0.f; acc[nf][3]=0.f; }
    for (int m = 0; m < 24; m++) {
      bf16x8 af = *(const bf16x8*)(A + pr * 1536 + ((kg * 16 + m * 64) ^ asw));
      bf16x8 wf[9];
#pragma unroll
      for (int nf = 0; nf < 9; nf++) {
        int j = wv * 144 + nf * 16 + lr;
        wf[nf] = *(const bf16x8*)(w_in_bf + (size_t)j * DD + kg * 8 + m * 32);
      }
#pragma unroll
      for (int nf = 0; nf < 9; nf++)
        acc[nf] = __builtin_amdgcn_mfma_f32_16x16x32_bf16(af, wf[nf], acc[nf], 0, 0, 0);
    }
    unsigned short* qkv = (unsigned short*)Bz;
#pragma unroll
    for (int nf = 0; nf < 9; nf++) {
      int j = wv * 144 + nf * 16 + lr;
      float bv = b_in[j];
#pragma unroll
      for (int r = 0; r < 4; r++) {
        int p = kg * 4 + r;
        if (p < 12) qkv[p * QSTR + j] = bf16_bits(acc[nf][r] + bv);
      }
    }
  }
  __syncthreads();

  // ---------------- Phase At: 12-head attention, o3 -> region A ------------
  {
    const unsigned short* qkv = (const unsigned short*)Bz;
    for (int e = t; e < 1728; e += 1024) {
      int h = e / 144, rem = e - h * 144, i = rem / 12, j = rem - i * 12;
      const unsigned short* qp = qkv + i * QSTR + h * 64;
      const unsigned short* kp = qkv + j * QSTR + 768 + h * 64;
      float s = 0.f;
#pragma unroll
      for (int d4 = 0; d4 < 16; d4++) {
        bf16x4 q4 = *(const bf16x4*)(qp + d4 * 4);
        bf16x4 k4 = *(const bf16x4*)(kp + d4 * 4);
#pragma unroll
        for (int e2 = 0; e2 < 4; e2++)
          s += bfu((unsigned short)q4[e2]) * bfu((unsigned short)k4[e2]);
      }
      scoresC[e] = s * 0.125f;
    }
    __syncthreads();
    if (t < 144) {
      int h = t / 12, i = t - h * 12;
      float* row = scoresC + h * 144 + i * 12;
      float m = -FLT_MAX;
#pragma unroll
      for (int j = 0; j < 12; j++) m = fmaxf(m, row[j]);
      float e2[12], sum = 0.f;
#pragma unroll
      for (int j = 0; j < 12; j++) { e2[j] = expf(row[j] - m); sum += e2[j]; }
      float inv = 1.f / sum;
#pragma unroll
      for (int j = 0; j < 12; j++) row[j] = e2[j] * inv;
    }
    __syncthreads();
    for (int q = t; q < 2304; q += 1024) {
      int i = q / 192, c4 = (q - i * 192) * 4;
      int h = c4 >> 6;
      const float* prow = scoresC + h * 144 + i * 12;
      float o0 = 0.f, o1 = 0.f, o2 = 0.f, o3v = 0.f;
#pragma unroll
      for (int j = 0; j < 12; j++) {
        bf16x4 v4 = *(const bf16x4*)(qkv + j * QSTR + 1536 + c4);
        float p = prow[j];
        o0 += p * bfu((unsigned short)v4[0]);
        o1 += p * bfu((unsigned short)v4[1]);
        o2 += p * bfu((unsigned short)v4[2]);
        o3v += p * bfu((unsigned short)v4[3]);
      }
      bf16x4 ov;
      ov[0] = (short)bf16_bits(o0); ov[1] = (short)bf16_bits(o1);
      ov[2] = (short)bf16_bits(o2); ov[3] = (short)bf16_bits(o3v);
      *(bf16x4*)(A + i * 1536 + ((2 * c4) ^ ((i & 7) << 4))) = ov;
    }
  }
  __syncthreads();

  // ---------------- Phase G2: aout = o3 @ w_out^T + b_out (f32, LDS) -------
  {
    int lr = ln & 15, kg = ln >> 4;
    int pr = lr < 12 ? lr : 11;
    int asw = (pr & 7) << 4;
    f32x4 acc[3];
#pragma unroll
    for (int jf = 0; jf < 3; jf++) { acc[jf][0]=0.f; acc[jf][1]=0.f; acc[jf][2]=0.f; acc[jf][3]=0.f; }
    for (int m = 0; m < 24; m++) {
      bf16x8 af = *(const bf16x8*)(A + pr * 1536 + ((kg * 16 + m * 64) ^ asw));
      bf16x8 wf[3];
#pragma unroll
      for (int jf = 0; jf < 3; jf++) {
        int j = wv * 48 + jf * 16 + lr;
        wf[jf] = *(const bf16x8*)(w_out_bf + (size_t)j * DD + kg * 8 + m * 32);
      }
#pragma unroll
      for (int jf = 0; jf < 3; jf++)
        acc[jf] = __builtin_amdgcn_mfma_f32_16x16x32_bf16(af, wf[jf], acc[jf], 0, 0, 0);
    }
    float* aout = (float*)Bz;
#pragma unroll
    for (int jf = 0; jf < 3; jf++) {
      int j = wv * 48 + jf * 16 + lr;
      float bv = b_out[j];
#pragma unroll
      for (int r = 0; r < 4; r++) {
        int p = kg * 4 + r;
        if (p < 12) aout[p * DD + j] = acc[jf][r] + bv;
      }
    }
  }
  __syncthreads();

  // ---------------- Phase L: LN2 + pool logits + softmax + pfeat + cls -----
  float* aout = (float*)Bz;
  float* pfeat = (float*)(Bz + 36864);
  float* fs = (float*)(Bz + 39936);     // 1536 f32
  float* raww = (float*)(Bz + 46080);   // 12
  float* a16 = (float*)(Bz + 46128);    // 16
  if (wv < 12) {
    int r = wv;
    float x[12], s1 = 0.f, s2 = 0.f;
#pragma unroll
    for (int k = 0; k < 12; k++) {
      x[k] = aout[r * DD + ln + 64 * k];
      s1 += x[k]; s2 += x[k] * x[k];
    }
#pragma unroll
    for (int off = 32; off > 0; off >>= 1) {
      s1 += __shfl_xor(s1, off); s2 += __shfl_xor(s2, off);
    }
    float m = s1 * (1.f / DD);
    float rstd = rsqrtf(s2 * (1.f / DD) - m * m + 1e-5f);
    float pl = 0.f;
#pragma unroll
    for (int k = 0; k < 12; k++) {
      int d = ln + 64 * k;
      float y = (x[k] - m) * rstd * ln2_g[d] + ln2_b[d];
      aout[r * DD + d] = y;
      pl += y * w_pool[d];
    }
#pragma unroll
    for (int off = 32; off > 0; off >>= 1) pl += __shfl_xor(pl, off);
    if (ln == 0) raww[r] = pl + b_pool[0];
  }
  __syncthreads();
  {
    float wts[12];
    float inv = 1.f / fmaxf(ptemp[0], 0.3f);
    float z[12], mx = -FLT_MAX;
#pragma unroll
    for (int p = 0; p < 12; p++) { z[p] = raww[p] * inv; mx = fmaxf(mx, z[p]); }
    float sme = 0.f;
#pragma unroll
    for (int p = 0; p < 12; p++) { z[p] = expf(z[p] - mx); sme += z[p]; }
    float is = 1.f / sme;
#pragma unroll
    for (int p = 0; p < 12; p++) wts[p] = z[p] * is;
    if (t < 768) {
      float s = 0.f;
#pragma unroll
      for (int p = 0; p < 12; p++) s += aout[p * DD + t] * wts[p];
      pfeat[t] = s;
      fs[t] = hidden[(size_t)b * NNtok * DD + t];  // cls token
    }
  }
  __syncthreads();

  // ---------------- Phase M: MLP GEMV + ReLU -> fs[768..1535] --------------
  if (t < 768) {
    const uint4* wr = (const uint4*)(w_mlp_bf + (size_t)t * DD);
    float acc2 = b_mlp[t];
    for (int k = 0; k < 96; k++) {
      uint4 w4 = wr[k];
      const float* pf = &pfeat[k * 8];
      acc2 += pf[0] * u2f(w4.x << 16) + pf[1] * u2f(w4.x & 0xFFFF0000u)
            + pf[2] * u2f(w4.y << 16) + pf[3] * u2f(w4.y & 0xFFFF0000u)
            + pf[4] * u2f(w4.z << 16) + pf[5] * u2f(w4.z & 0xFFFF0000u)
            + pf[6] * u2f(w4.w << 16) + pf[7] * u2f(w4.w & 0xFFFF0000u);
    }
    fs[768 + t] = fmaxf(acc2, 0.f);
  }
  __syncthreads();

  // ---------------- Phase F: fusion norm -----------------------------------
  {
    float s = fs[t] * fs[t];
    if (t < 512) { float v = fs[t + 1024]; s += v * v; }
#pragma unroll
    for (int off = 32; off > 0; off >>= 1) s += __shfl_xor(s, off);
    if (ln == 0) a16[wv] = s;
  }
  __syncthreads();
  float rnf;
  {
    float tot = 0.f;
#pragma unroll
    for (int i = 0; i < 16; i++) tot += a16[i];
    rnf = rsqrtf(tot);
  }

  // ---------------- Phase A: ArcFace, wave wv -> classes wv, wv+16, ... ----
  {
    int lab = labels[b];
    const float cos_m = 0.8775825618903728f, sin_m = 0.479425538604203f;
    const float th = -0.8775825618903728f, mm = 0.2397127693021015f;
    for (int c = wv; c < CC; c += 16) {
      const float* wr = arc_w + (size_t)c * 1536;
      float acc = 0.f, nw = 0.f;
#pragma unroll
      for (int k = 0; k < 24; k++) {
        int d = ln + 64 * k;
        float a = fs[d], w = wr[d];
        acc += a * w; nw += w * w;
      }
#pragma unroll
      for (int off = 32; off > 0; off >>= 1) {
        acc += __shfl_xor(acc, off); nw += __shfl_xor(nw, off);
      }
      if (ln == 0) {
        float cosv = acc * rsqrtf(nw) * rnf;
        float s2 = 1.f - cosv * cosv;
        s2 = fminf(fmaxf(s2, 0.f), 1.f);
        float sinv = sqrtf(s2);
        float phi = cosv * cos_m - sinv * sin_m;
        phi = (cosv > th) ? phi : (cosv - mm);
        out[(size_t)b * CC + c] = ((c == lab) ? phi : cosv) * 30.f;
      }
    }
  }
}

extern "C" void kernel_launch(void* const* d_in, const int* in_sizes, int n_in,
                              void* d_out, int out_size, void* d_ws, size_t ws_size,
                              hipStream_t stream) {
  const float* hidden = (const float*)d_in[0];
  const float* attns  = (const float*)d_in[1];
  const int*   labels = (const int*)d_in[2];
  const float* ln1_g  = (const float*)d_in[3];
  const float* ln1_b  = (const float*)d_in[4];
  const float* w_in   = (const float*)d_in[5];
  const float* b_in   = (const float*)d_in[6];
  const float* w_out  = (const float*)d_in[7];
  const float* b_out  = (const float*)d_in[8];
  const float* ln2_g  = (const float*)d_in[9];
  const float* ln2_b  = (const float*)d_in[10];
  const float* w_pool = (const float*)d_in[11];
  const float* b_pool = (const float*)d_in[12];
  const float* ptemp  = (const float*)d_in[13];
  const float* w_mlp  = (const float*)d_in[14];
  const float* b_mlp  = (const float*)d_in[15];
  const float* arc_w  = (const float*)d_in[16];
  float* outp = (float*)d_out;

  float* F = (float*)d_ws;
  __hip_bfloat16* w_in_bf  = (__hip_bfloat16*)F;               // 1769472 bf16
  __hip_bfloat16* w_out_bf = (__hip_bfloat16*)(F + 884736);    // 589824 bf16
  __hip_bfloat16* w_mlp_bf = (__hip_bfloat16*)(F + 1179648);   // 589824 bf16

  k1_cast<<<256, 256, 0, stream>>>(w_in, w_out, w_mlp, w_in_bf, w_out_bf,
                                   w_mlp_bf);
  k2_all<<<BB, 1024, 0, stream>>>(hidden, attns, labels, ln1_g, ln1_b, w_in_bf,
                                  b_in, w_out_bf, b_out, ln2_g, ln2_b, w_pool,
                                  b_pool, ptemp, w_mlp_bf, b_mlp, arc_w, outp);
}

// Round 10
// 191.373 us; speedup vs baseline: 1.5232x; 1.0757x over previous
//
#include <hip/hip_runtime.h>
#include <hip/hip_bf16.h>
#include <float.h>
#include <math.h>

#define BB 64
#define NNtok 197
#define DD 768
#define HH 12
#define PP 12
#define CC 200
#define NPATCH 196

typedef short bf16x8 __attribute__((ext_vector_type(8)));
typedef float f32x4 __attribute__((ext_vector_type(4)));

__device__ __forceinline__ unsigned short bf16_bits(float x) {
  __hip_bfloat16 h = __float2bfloat16(x);
  return *reinterpret_cast<unsigned short*>(&h);
}
__device__ __forceinline__ float u2f(unsigned int u) {
  union { unsigned int u; float f; } cv; cv.u = u; return cv.f;
}
__device__ __forceinline__ float bfu(unsigned short us) {
  union { unsigned int u; float f; } cv; cv.u = ((unsigned int)us) << 16; return cv.f;
}

// ============ K1: cast weights to bf16 + reset tail counters ================
__global__ __launch_bounds__(256) void k1_cast(
    const float* __restrict__ w1, const float* __restrict__ w2,
    const float* __restrict__ w3, __hip_bfloat16* __restrict__ o1,
    __hip_bfloat16* __restrict__ o2, __hip_bfloat16* __restrict__ o3,
    int* __restrict__ cnt) {
  if (blockIdx.x == 0 && threadIdx.x < 64) cnt[threadIdx.x] = 0;
  for (int i = blockIdx.x * 256 + threadIdx.x; i < 737280; i += 256 * 256) {
    const float* src; __hip_bfloat16* dst; int off;
    if (i < 442368) { src = w1; dst = o1; off = i; }
    else if (i < 589824) { src = w2; dst = o2; off = i - 442368; }
    else { src = w3; dst = o3; off = i - 589824; }
    float4 v = ((const float4*)src)[off];
    union { unsigned short u[4]; ushort4 v4; } p;
    p.u[0] = bf16_bits(v.x); p.u[1] = bf16_bits(v.y);
    p.u[2] = bf16_bits(v.z); p.u[3] = bf16_bits(v.w);
    ((ushort4*)dst)[off] = p.v4;
  }
}

// ============ K2: per (b,hg) full mid pipeline; last-arriver runs tail ======
// LDS (bytes): parts bf16[12][776] @0..18624 | sc f32[256] @18624 (select only)
//   qkv bf16[3*16*192] @18624..37056 | scores f32[432] @37056..38784
//   o3 bf16[16][200] @38784..45184 | sel int[12] @45184
//   TAIL: aout f32[12][768] @0..36864 | pfeat @36864 | fs f32[1536] @39936
//         raww @46080 | a16 @46128 | is_last @46192
__global__ __launch_bounds__(256) void k2_all(
    const float* __restrict__ hidden, const float* __restrict__ attns,
    const int* __restrict__ labels, const float* __restrict__ ln1_g,
    const float* __restrict__ ln1_b, const __hip_bfloat16* __restrict__ w_in_bf,
    const float* __restrict__ b_in, const __hip_bfloat16* __restrict__ w_out_bf,
    const float* __restrict__ b_out, const float* __restrict__ ln2_g,
    const float* __restrict__ ln2_b, const float* __restrict__ w_pool,
    const float* __restrict__ b_pool, const float* __restrict__ ptemp,
    const __hip_bfloat16* __restrict__ w_mlp_bf, const float* __restrict__ b_mlp,
    const float* __restrict__ arc_w, float* __restrict__ out,
    float* __restrict__ part_ws, int* __restrict__ cnt) {
  __shared__ __align__(16) char sm[46208];
  int t = threadIdx.x, blk = blockIdx.x;
  int wv = t >> 6, ln = t & 63;
  int b = ((blk >> 3) << 1) | (blk & 1);  // hg pinned to XCD pair
  int hg = (blk >> 1) & 3;
  unsigned short* parts = (unsigned short*)sm;            // [12][776]
  float* sc = (float*)(sm + 18624);
  unsigned short* qkv = (unsigned short*)(sm + 18624);    // [3][16][192]
  float* scores = (float*)(sm + 37056);                   // [3][12][12]
  unsigned short* o3 = (unsigned short*)(sm + 38784);     // [16][200]
  int* sel = (int*)(sm + 45184);

  // ---------------- Phase S: scores + top-12 (redundant per hg) ------------
  {
    float acc = -FLT_MAX;
    if (t < NPATCH) {
      acc = 0.f;
#pragma unroll
      for (int l = 0; l < 4; l++) {
        float part = 0.f;
#pragma unroll
        for (int h = 0; h < HH; h++) {
          size_t base = (size_t)((l * BB + b) * HH + h) * ((size_t)NNtok * NNtok);
          part += attns[base + 1 + t];
        }
        acc += part * (1.f / 12.f);
      }
      acc *= 0.25f;
    }
    sc[t] = acc;
    __syncthreads();
    if (t < 64) {
      float v[4]; int idx[4];
#pragma unroll
      for (int j = 0; j < 4; j++) { idx[j] = t + j * 64; v[j] = sc[idx[j]]; }
      for (int it = 0; it < PP; ++it) {
        float bv = v[0]; int bidx = idx[0];
#pragma unroll
        for (int j = 1; j < 4; j++)
          if (v[j] > bv || (v[j] == bv && idx[j] < bidx)) { bv = v[j]; bidx = idx[j]; }
        float cv = bv; int ci = bidx;
#pragma unroll
        for (int off = 32; off > 0; off >>= 1) {
          float ov = __shfl_xor(cv, off); int oi = __shfl_xor(ci, off);
          if (ov > cv || (ov == cv && oi < ci)) { cv = ov; ci = oi; }
        }
        if (t == 0) sel[it] = ci;
#pragma unroll
        for (int j = 0; j < 4; j++)
          if (idx[j] == ci) v[j] = -FLT_MAX;
      }
    }
    __syncthreads();
    // gather + LN1 -> parts LDS (wave wv owns rows wv*3..wv*3+2)
#pragma unroll
    for (int q = 0; q < 3; q++) {
      int i = wv * 3 + q;
      const float* row = hidden + ((size_t)b * NNtok + 1 + sel[i]) * DD;
      float x[12], s1 = 0.f, s2 = 0.f;
#pragma unroll
      for (int k = 0; k < 12; k++) {
        x[k] = row[ln + 64 * k];
        s1 += x[k]; s2 += x[k] * x[k];
      }
#pragma unroll
      for (int off = 32; off > 0; off >>= 1) {
        s1 += __shfl_xor(s1, off); s2 += __shfl_xor(s2, off);
      }
      float m = s1 * (1.f / DD);
      float rstd = rsqrtf(s2 * (1.f / DD) - m * m + 1e-5f);
#pragma unroll
      for (int k = 0; k < 12; k++) {
        int d = ln + 64 * k;
        parts[i * 776 + d] = bf16_bits((x[k] - m) * rstd * ln1_g[d] + ln1_b[d]);
      }
    }
  }
  __syncthreads();

  // ---------------- Phase G1: qkv slice = parts @ W_in[hg slice]^T ---------
  {
    int lr = ln & 15, kg = ln >> 4;
    int pr = lr < 12 ? lr : 11;
    int wrow[9];
#pragma unroll
    for (int nf = 0; nf < 9; nf++) {
      int lc = wv * 144 + nf * 16 + lr;
      int s = lc / 192, d2 = lc - s * 192;
      wrow[nf] = s * 768 + hg * 192 + d2;
    }
    f32x4 acc[9];
#pragma unroll
    for (int nf = 0; nf < 9; nf++) { acc[nf][0]=0.f; acc[nf][1]=0.f; acc[nf][2]=0.f; acc[nf][3]=0.f; }
    for (int m = 0; m < 24; m++) {
      bf16x8 af = *(const bf16x8*)(parts + pr * 776 + kg * 8 + m * 32);
      bf16x8 wf[9];
#pragma unroll
      for (int nf = 0; nf < 9; nf++)
        wf[nf] = *(const bf16x8*)(w_in_bf + (size_t)wrow[nf] * DD + kg * 8 + m * 32);
#pragma unroll
      for (int nf = 0; nf < 9; nf++)
        acc[nf] = __builtin_amdgcn_mfma_f32_16x16x32_bf16(af, wf[nf], acc[nf], 0, 0, 0);
    }
    __syncthreads();  // parts LDS free before qkv overwrite (aliased region!)
#pragma unroll
    for (int nf = 0; nf < 9; nf++) {
      int lc = wv * 144 + nf * 16 + lr;
      int s = lc / 192, d2 = lc - s * 192;
      float bv = b_in[s * 768 + hg * 192 + d2];
#pragma unroll
      for (int r = 0; r < 4; r++) {
        int p = kg * 4 + r;
        if (p < 12) qkv[(s * 16 + p) * 192 + d2] = bf16_bits(acc[nf][r] + bv);
      }
    }
  }
  __syncthreads();

  // ---------------- Phase At: 3-head attention -----------------------------
  {
    for (int e = t; e < 432; e += 256) {
      int h = e / 144, rem = e - h * 144;
      int i = rem / 12, j = rem - i * 12;
      float s = 0.f;
#pragma unroll
      for (int d = 0; d < 64; d++)
        s += bfu(qkv[(0 * 16 + i) * 192 + h * 64 + d]) *
             bfu(qkv[(1 * 16 + j) * 192 + h * 64 + d]);
      scores[e] = s * 0.125f;
    }
    __syncthreads();
    if (t < 36) {
      int h = t / 12, i = t - h * 12;
      float* row = scores + h * 144 + i * 12;
      float m = -FLT_MAX;
#pragma unroll
      for (int j = 0; j < 12; j++) m = fmaxf(m, row[j]);
      float e2[12], sum = 0.f;
#pragma unroll
      for (int j = 0; j < 12; j++) { e2[j] = expf(row[j] - m); sum += e2[j]; }
      float inv = 1.f / sum;
#pragma unroll
      for (int j = 0; j < 12; j++) row[j] = e2[j] * inv;
    }
    __syncthreads();
    for (int o = t; o < 2304; o += 256) {
      int i = o / 192, d2 = o - i * 192;
      int h = d2 >> 6;
      float s = 0.f;
#pragma unroll
      for (int j = 0; j < 12; j++)
        s += scores[h * 144 + i * 12 + j] * bfu(qkv[(2 * 16 + j) * 192 + d2]);
      o3[i * 200 + d2] = bf16_bits(s);
    }
  }
  __syncthreads();

  // ---------------- Phase G2: partial wout -> part_ws ----------------------
  {
    int lr = ln & 15, kg = ln >> 4;
    f32x4 acc2[12];
#pragma unroll
    for (int jf = 0; jf < 12; jf++) { acc2[jf][0]=0.f; acc2[jf][1]=0.f; acc2[jf][2]=0.f; acc2[jf][3]=0.f; }
    const unsigned short* Ob = o3 + lr * 200 + kg * 8;
    for (int k0 = 0; k0 < 192; k0 += 32) {
      bf16x8 af = *(const bf16x8*)(Ob + k0);
      bf16x8 wf[12];
#pragma unroll
      for (int jf = 0; jf < 12; jf++) {
        int j = wv * 192 + jf * 16 + lr;
        wf[jf] = *(const bf16x8*)(w_out_bf + (size_t)j * DD + hg * 192 + kg * 8 + k0);
      }
#pragma unroll
      for (int jf = 0; jf < 12; jf++)
        acc2[jf] = __builtin_amdgcn_mfma_f32_16x16x32_bf16(af, wf[jf], acc2[jf], 0, 0, 0);
    }
#pragma unroll
    for (int jf = 0; jf < 12; jf++) {
      int j = wv * 192 + jf * 16 + lr;
#pragma unroll
      for (int r = 0; r < 4; r++) {
        int p = kg * 4 + r;
        if (p < 12)
          part_ws[(((size_t)b * 4 + hg) * 12 + p) * DD + j] = acc2[jf][r];
      }
    }
  }

  // ---------------- Arrival: last of 4 blocks for b runs the tail ----------
  __threadfence();
  __syncthreads();
  int* is_last = (int*)(sm + 46192);
  if (t == 0) {
    int old = atomicAdd(&cnt[b], 1);
    *is_last = (old == 3);
  }
  __syncthreads();
  if (!*is_last) return;
  __threadfence();  // acquire: invalidate caches before reading partials
  __syncthreads();

  // ---------------- TAIL: reduce + LN2 + pool + MLP + fusion + ArcFace -----
  float* aout = (float*)sm;            // [12][768]
  float* pfeat = (float*)(sm + 36864);
  float* fs = (float*)(sm + 39936);    // 1536
  float* raww = (float*)(sm + 46080);
  float* a16 = (float*)(sm + 46128);
  for (int u = t; u < 9216; u += 256) {
    int j = u % 768;
    float s = b_out[j];
#pragma unroll
    for (int g4 = 0; g4 < 4; g4++)
      s += part_ws[(((size_t)b * 4 + g4) * 12) * DD + u];
    aout[u] = s;
  }
  __syncthreads();
#pragma unroll
  for (int q = 0; q < 3; q++) {
    int r = wv * 3 + q;
    float x[12], s1 = 0.f, s2 = 0.f;
#pragma unroll
    for (int k = 0; k < 12; k++) {
      x[k] = aout[r * DD + ln + 64 * k];
      s1 += x[k]; s2 += x[k] * x[k];
    }
#pragma unroll
    for (int off = 32; off > 0; off >>= 1) {
      s1 += __shfl_xor(s1, off); s2 += __shfl_xor(s2, off);
    }
    float m = s1 * (1.f / DD);
    float rstd = rsqrtf(s2 * (1.f / DD) - m * m + 1e-5f);
    float pl = 0.f;
#pragma unroll
    for (int k = 0; k < 12; k++) {
      int d = ln + 64 * k;
      float y = (x[k] - m) * rstd * ln2_g[d] + ln2_b[d];
      aout[r * DD + d] = y;
      pl += y * w_pool[d];
    }
#pragma unroll
    for (int off = 32; off > 0; off >>= 1) pl += __shfl_xor(pl, off);
    if (ln == 0) raww[r] = pl + b_pool[0];
  }
  __syncthreads();
  {
    float wts[12];
    float inv = 1.f / fmaxf(ptemp[0], 0.3f);
    float z[12], mx = -FLT_MAX;
#pragma unroll
    for (int p = 0; p < 12; p++) { z[p] = raww[p] * inv; mx = fmaxf(mx, z[p]); }
    float sme = 0.f;
#pragma unroll
    for (int p = 0; p < 12; p++) { z[p] = expf(z[p] - mx); sme += z[p]; }
    float is = 1.f / sme;
#pragma unroll
    for (int p = 0; p < 12; p++) wts[p] = z[p] * is;
    for (int d = t; d < 768; d += 256) {
      float s = 0.f;
#pragma unroll
      for (int p = 0; p < 12; p++) s += aout[p * DD + d] * wts[p];
      pfeat[d] = s;
      fs[d] = hidden[(size_t)b * NNtok * DD + d];  // cls token
    }
  }
  __syncthreads();
  for (int j = t; j < 768; j += 256) {
    const uint4* wr = (const uint4*)(w_mlp_bf + (size_t)j * DD);
    float acc2 = b_mlp[j];
    for (int k = 0; k < 96; k++) {
      uint4 w4 = wr[k];
      const float* pf = &pfeat[k * 8];
      acc2 += pf[0] * u2f(w4.x << 16) + pf[1] * u2f(w4.x & 0xFFFF0000u)
            + pf[2] * u2f(w4.y << 16) + pf[3] * u2f(w4.y & 0xFFFF0000u)
            + pf[4] * u2f(w4.z << 16) + pf[5] * u2f(w4.z & 0xFFFF0000u)
            + pf[6] * u2f(w4.w << 16) + pf[7] * u2f(w4.w & 0xFFFF0000u);
    }
    fs[768 + j] = fmaxf(acc2, 0.f);
  }
  __syncthreads();
  {
    float s = 0.f;
    for (int u = t; u < 1536; u += 256) { float v = fs[u]; s += v * v; }
#pragma unroll
    for (int off = 32; off > 0; off >>= 1) s += __shfl_xor(s, off);
    if (ln == 0) a16[wv] = s;
  }
  __syncthreads();
  float rnf = rsqrtf(a16[0] + a16[1] + a16[2] + a16[3]);
  {
    int lab = labels[b];
    const float cos_m = 0.8775825618903728f, sin_m = 0.479425538604203f;
    const float th = -0.8775825618903728f, mm = 0.2397127693021015f;
    for (int c = wv; c < CC; c += 4) {
      const float* wr = arc_w + (size_t)c * 1536;
      float acc = 0.f, nw = 0.f;
#pragma unroll
      for (int k = 0; k < 24; k++) {
        int d = ln + 64 * k;
        float a = fs[d], w = wr[d];
        acc += a * w; nw += w * w;
      }
#pragma unroll
      for (int off = 32; off > 0; off >>= 1) {
        acc += __shfl_xor(acc, off); nw += __shfl_xor(nw, off);
      }
      if (ln == 0) {
        float cosv = acc * rsqrtf(nw) * rnf;
        float s2 = 1.f - cosv * cosv;
        s2 = fminf(fmaxf(s2, 0.f), 1.f);
        float sinv = sqrtf(s2);
        float phi = cosv * cos_m - sinv * sin_m;
        phi = (cosv > th) ? phi : (cosv - mm);
        out[(size_t)b * CC + c] = ((c == lab) ? phi : cosv) * 30.f;
      }
    }
  }
}

extern "C" void kernel_launch(void* const* d_in, const int* in_sizes, int n_in,
                              void* d_out, int out_size, void* d_ws, size_t ws_size,
                              hipStream_t stream) {
  const float* hidden = (const float*)d_in[0];
  const float* attns  = (const float*)d_in[1];
  const int*   labels = (const int*)d_in[2];
  const float* ln1_g  = (const float*)d_in[3];
  const float* ln1_b  = (const float*)d_in[4];
  const float* w_in   = (const float*)d_in[5];
  const float* b_in   = (const float*)d_in[6];
  const float* w_out  = (const float*)d_in[7];
  const float* b_out  = (const float*)d_in[8];
  const float* ln2_g  = (const float*)d_in[9];
  const float* ln2_b  = (const float*)d_in[10];
  const float* w_pool = (const float*)d_in[11];
  const float* b_pool = (const float*)d_in[12];
  const float* ptemp  = (const float*)d_in[13];
  const float* w_mlp  = (const float*)d_in[14];
  const float* b_mlp  = (const float*)d_in[15];
  const float* arc_w  = (const float*)d_in[16];
  float* outp = (float*)d_out;

  float* F = (float*)d_ws;
  __hip_bfloat16* w_in_bf  = (__hip_bfloat16*)F;               // 1769472 bf16
  __hip_bfloat16* w_out_bf = (__hip_bfloat16*)(F + 884736);    // 589824 bf16
  __hip_bfloat16* w_mlp_bf = (__hip_bfloat16*)(F + 1179648);   // 589824 bf16
  float* part_ws = F + 1474560;                                // 2359296 f32
  int* cnt = (int*)(F + 3833856);                              // 64 ints

  k1_cast<<<256, 256, 0, stream>>>(w_in, w_out, w_mlp, w_in_bf, w_out_bf,
                                   w_mlp_bf, cnt);
  k2_all<<<256, 256, 0, stream>>>(hidden, attns, labels, ln1_g, ln1_b, w_in_bf,
                                  b_in, w_out_bf, b_out, ln2_g, ln2_b, w_pool,
                                  b_pool, ptemp, w_mlp_bf, b_mlp, arc_w, outp,
                                  part_ws, cnt);
}

// Round 11
// 143.927 us; speedup vs baseline: 2.0254x; 1.3296x over previous
//
#include <hip/hip_runtime.h>
#include <hip/hip_bf16.h>
#include <float.h>
#include <math.h>

#define BB 64
#define NNtok 197
#define DD 768
#define HH 12
#define PP 12
#define CC 200
#define NPATCH 196

typedef short bf16x8 __attribute__((ext_vector_type(8)));
typedef float f32x4 __attribute__((ext_vector_type(4)));

__device__ __forceinline__ unsigned short bf16_bits(float x) {
  __hip_bfloat16 h = __float2bfloat16(x);
  return *reinterpret_cast<unsigned short*>(&h);
}
__device__ __forceinline__ float u2f(unsigned int u) {
  union { unsigned int u; float f; } cv; cv.u = u; return cv.f;
}
__device__ __forceinline__ float bfu(unsigned short us) {
  union { unsigned int u; float f; } cv; cv.u = ((unsigned int)us) << 16; return cv.f;
}

// ================= K1: select+top12+LN1 (blk<64) | weight casts =============
__global__ __launch_bounds__(256) void k1_front(
    const float* __restrict__ hidden, const float* __restrict__ attns,
    const float* __restrict__ g, const float* __restrict__ be,
    const float* __restrict__ w1, const float* __restrict__ w2,
    const float* __restrict__ w3, __hip_bfloat16* __restrict__ o1,
    __hip_bfloat16* __restrict__ o2, __hip_bfloat16* __restrict__ o3,
    __hip_bfloat16* __restrict__ parts) {
  int t = threadIdx.x, bi = blockIdx.x;
  if (bi >= 64) {
    for (int i = (bi - 64) * 256 + t; i < 737280; i += 256 * 256) {
      const float* src; __hip_bfloat16* dst; int off;
      if (i < 442368) { src = w1; dst = o1; off = i; }
      else if (i < 589824) { src = w2; dst = o2; off = i - 442368; }
      else { src = w3; dst = o3; off = i - 589824; }
      float4 v = ((const float4*)src)[off];
      union { unsigned short u[4]; ushort4 v4; } p;
      p.u[0] = bf16_bits(v.x); p.u[1] = bf16_bits(v.y);
      p.u[2] = bf16_bits(v.z); p.u[3] = bf16_bits(v.w);
      ((ushort4*)dst)[off] = p.v4;
    }
    return;
  }
  int b = bi;
  __shared__ float sc[256];
  __shared__ int sel_s[PP];
  int wv = t >> 6, ln = t & 63;
  float acc = -FLT_MAX;
  if (t < NPATCH) {
    acc = 0.f;
#pragma unroll
    for (int l = 0; l < 4; l++) {
      float part = 0.f;
#pragma unroll
      for (int h = 0; h < HH; h++) {
        size_t base = (size_t)((l * BB + b) * HH + h) * ((size_t)NNtok * NNtok);
        part += attns[base + 1 + t];
      }
      acc += part * (1.f / 12.f);
    }
    acc *= 0.25f;
  }
  sc[t] = acc;
  __syncthreads();
  if (t < 64) {
    float v[4]; int idx[4];
#pragma unroll
    for (int j = 0; j < 4; j++) { idx[j] = t + j * 64; v[j] = sc[idx[j]]; }
    for (int it = 0; it < PP; ++it) {
      float bv = v[0]; int bidx = idx[0];
#pragma unroll
      for (int j = 1; j < 4; j++)
        if (v[j] > bv || (v[j] == bv && idx[j] < bidx)) { bv = v[j]; bidx = idx[j]; }
      float cv = bv; int ci = bidx;
#pragma unroll
      for (int off = 32; off > 0; off >>= 1) {
        float ov = __shfl_xor(cv, off); int oi = __shfl_xor(ci, off);
        if (ov > cv || (ov == cv && oi < ci)) { cv = ov; ci = oi; }
      }
      if (t == 0) sel_s[it] = ci;
#pragma unroll
      for (int j = 0; j < 4; j++)
        if (idx[j] == ci) v[j] = -FLT_MAX;
    }
  }
  __syncthreads();
#pragma unroll
  for (int q = 0; q < 3; q++) {
    int i = wv * 3 + q;
    const float* row = hidden + ((size_t)b * NNtok + 1 + sel_s[i]) * DD;
    float x[12], s1 = 0.f, s2 = 0.f;
#pragma unroll
    for (int k = 0; k < 12; k++) {
      x[k] = row[ln + 64 * k];
      s1 += x[k]; s2 += x[k] * x[k];
    }
#pragma unroll
    for (int off = 32; off > 0; off >>= 1) {
      s1 += __shfl_xor(s1, off); s2 += __shfl_xor(s2, off);
    }
    float m = s1 * (1.f / DD);
    float rstd = rsqrtf(s2 * (1.f / DD) - m * m + 1e-5f);
    __hip_bfloat16* outp_ = parts + ((size_t)b * PP + i) * DD;
#pragma unroll
    for (int k = 0; k < 12; k++) {
      int d = ln + 64 * k;
      outp_[d] = __float2bfloat16((x[k] - m) * rstd * g[d] + be[d]);
    }
  }
}

// ====== K2: per (b,hg): qkv-slice GEMM + 3-head attention + partial wout ====
__global__ __launch_bounds__(256) void k2_mid(
    const __hip_bfloat16* __restrict__ parts, const __hip_bfloat16* __restrict__ w_in_bf,
    const float* __restrict__ b_in, const __hip_bfloat16* __restrict__ w_out_bf,
    float* __restrict__ part_ws) {
  int bi = blockIdx.x;
  int b = bi >> 2, hg = bi & 3;  // hg = XCD&3 under round-robin: slice L2-pinned
  int t = threadIdx.x;
  int wave = t >> 6, lane = t & 63, lr = lane & 15, kg = lane >> 4;
  __shared__ __align__(16) unsigned short qkv3[3][16][192];
  __shared__ __align__(16) unsigned short o3[16][192];
  __shared__ float scores[432];

  int pr = lr < 12 ? lr : 11;
  const __hip_bfloat16* Ab = parts + ((size_t)b * 12 + pr) * DD + kg * 8;
  int wrow[9];
#pragma unroll
  for (int nf = 0; nf < 9; nf++) {
    int lc = wave * 144 + nf * 16 + lr;
    int s = lc / 192, d2 = lc - s * 192;
    wrow[nf] = s * 768 + hg * 192 + d2;
  }
  f32x4 acc[9];
#pragma unroll
  for (int nf = 0; nf < 9; nf++) { acc[nf][0]=0.f; acc[nf][1]=0.f; acc[nf][2]=0.f; acc[nf][3]=0.f; }
  for (int k0 = 0; k0 < 768; k0 += 32) {
    bf16x8 af = *(const bf16x8*)(Ab + k0);
    bf16x8 wf[9];
#pragma unroll
    for (int nf = 0; nf < 9; nf++)
      wf[nf] = *(const bf16x8*)(w_in_bf + (size_t)wrow[nf] * DD + kg * 8 + k0);
#pragma unroll
    for (int nf = 0; nf < 9; nf++)
      acc[nf] = __builtin_amdgcn_mfma_f32_16x16x32_bf16(af, wf[nf], acc[nf], 0, 0, 0);
  }
#pragma unroll
  for (int nf = 0; nf < 9; nf++) {
    int lc = wave * 144 + nf * 16 + lr;
    int s = lc / 192, d2 = lc - s * 192;
    float bv = b_in[s * 768 + hg * 192 + d2];
#pragma unroll
    for (int r = 0; r < 4; r++) {
      int p = kg * 4 + r;
      qkv3[s][p][d2] = bf16_bits(acc[nf][r] + bv);
    }
  }
  __syncthreads();

  for (int e = t; e < 432; e += 256) {
    int h = e / 144, rem = e - h * 144;
    int i = rem / 12, j = rem - i * 12;
    float s = 0.f;
#pragma unroll
    for (int d = 0; d < 64; d++)
      s += bfu(qkv3[0][i][h * 64 + d]) * bfu(qkv3[1][j][h * 64 + d]);
    scores[e] = s * 0.125f;
  }
  __syncthreads();
  if (t < 36) {
    int h = t / 12, i = t - h * 12;
    float* row = scores + h * 144 + i * 12;
    float m = -FLT_MAX;
#pragma unroll
    for (int j = 0; j < 12; j++) m = fmaxf(m, row[j]);
    float e2[12], sum = 0.f;
#pragma unroll
    for (int j = 0; j < 12; j++) { e2[j] = expf(row[j] - m); sum += e2[j]; }
    float inv = 1.f / sum;
#pragma unroll
    for (int j = 0; j < 12; j++) row[j] = e2[j] * inv;
  }
  __syncthreads();
  for (int o = t; o < 2304; o += 256) {
    int i = o / 192, d2 = o - i * 192;
    int h = d2 >> 6;
    float s = 0.f;
#pragma unroll
    for (int j = 0; j < 12; j++)
      s += scores[h * 144 + i * 12 + j] * bfu(qkv3[2][j][d2]);
    o3[i][d2] = bf16_bits(s);
  }
  __syncthreads();

  f32x4 acc2[12];
#pragma unroll
  for (int jf = 0; jf < 12; jf++) { acc2[jf][0]=0.f; acc2[jf][1]=0.f; acc2[jf][2]=0.f; acc2[jf][3]=0.f; }
  const unsigned short* Ob = &o3[0][0] + lr * 192 + kg * 8;
  for (int k0 = 0; k0 < 192; k0 += 32) {
    bf16x8 af = *(const bf16x8*)(Ob + k0);
    bf16x8 wf[12];
#pragma unroll
    for (int jf = 0; jf < 12; jf++) {
      int j = wave * 192 + jf * 16 + lr;
      wf[jf] = *(const bf16x8*)(w_out_bf + (size_t)j * DD + hg * 192 + kg * 8 + k0);
    }
#pragma unroll
    for (int jf = 0; jf < 12; jf++)
      acc2[jf] = __builtin_amdgcn_mfma_f32_16x16x32_bf16(af, wf[jf], acc2[jf], 0, 0, 0);
  }
#pragma unroll
  for (int jf = 0; jf < 12; jf++) {
    int j = wave * 192 + jf * 16 + lr;
#pragma unroll
    for (int r = 0; r < 4; r++) {
      int p = kg * 4 + r;
      if (p < 12)
        part_ws[(((size_t)b * 4 + hg) * 12 + p) * DD + j] = acc2[jf][r];
    }
  }
}

// ====== K3: per b: reduce partials + LN2 + pool + MLP + fusion + ArcFace ====
__global__ __launch_bounds__(256) void k3_tail(
    const float* __restrict__ part_ws, const float* __restrict__ b_out,
    const float* __restrict__ g, const float* __restrict__ be,
    const float* __restrict__ wp, const float* __restrict__ bp,
    const float* __restrict__ ptemp, const __hip_bfloat16* __restrict__ wmlp,
    const float* __restrict__ bmlp, const float* __restrict__ hidden,
    const float* __restrict__ arc_w, const int* __restrict__ labels,
    float* __restrict__ out) {
  int b = blockIdx.x;
  int t = threadIdx.x, wv = t >> 6, ln = t & 63;
  __shared__ __align__(16) float aout[12 * 768];
  __shared__ float pfeat[768];
  __shared__ __align__(16) float fs[1536];
  __shared__ float raww[12];
  __shared__ float a4[4];
  for (int u = t; u < 9216; u += 256) {
    int j = u % 768;
    float s = b_out[j];
#pragma unroll
    for (int g4 = 0; g4 < 4; g4++)
      s += part_ws[(((size_t)b * 4 + g4) * 12) * DD + u];
    aout[u] = s;
  }
  __syncthreads();
#pragma unroll
  for (int q = 0; q < 3; q++) {
    int r = wv * 3 + q;
    float x[12], s1 = 0.f, s2 = 0.f;
#pragma unroll
    for (int k = 0; k < 12; k++) {
      x[k] = aout[r * DD + ln + 64 * k];
      s1 += x[k]; s2 += x[k] * x[k];
    }
#pragma unroll
    for (int off = 32; off > 0; off >>= 1) {
      s1 += __shfl_xor(s1, off); s2 += __shfl_xor(s2, off);
    }
    float m = s1 * (1.f / DD);
    float rstd = rsqrtf(s2 * (1.f / DD) - m * m + 1e-5f);
    float pl = 0.f;
#pragma unroll
    for (int k = 0; k < 12; k++) {
      int d = ln + 64 * k;
      float y = (x[k] - m) * rstd * g[d] + be[d];
      aout[r * DD + d] = y;
      pl += y * wp[d];
    }
#pragma unroll
    for (int off = 32; off > 0; off >>= 1) pl += __shfl_xor(pl, off);
    if (ln == 0) raww[r] = pl + bp[0];
  }
  __syncthreads();
  {
    float wts[12];
    float inv = 1.f / fmaxf(ptemp[0], 0.3f);
    float z[12], mx = -FLT_MAX;
#pragma unroll
    for (int p = 0; p < 12; p++) { z[p] = raww[p] * inv; mx = fmaxf(mx, z[p]); }
    float sme = 0.f;
#pragma unroll
    for (int p = 0; p < 12; p++) { z[p] = expf(z[p] - mx); sme += z[p]; }
    float is = 1.f / sme;
#pragma unroll
    for (int p = 0; p < 12; p++) wts[p] = z[p] * is;
    for (int d = t; d < 768; d += 256) {
      float s = 0.f;
#pragma unroll
      for (int p = 0; p < 12; p++) s += aout[p * DD + d] * wts[p];
      pfeat[d] = s;
      fs[d] = hidden[(size_t)b * NNtok * DD + d];  // cls token
    }
  }
  __syncthreads();
  for (int j = t; j < 768; j += 256) {
    const uint4* wr = (const uint4*)(wmlp + (size_t)j * DD);
    float acc2 = bmlp[j];
    for (int k = 0; k < 96; k++) {
      uint4 w4 = wr[k];
      const float* pf = &pfeat[k * 8];
      acc2 += pf[0] * u2f(w4.x << 16) + pf[1] * u2f(w4.x & 0xFFFF0000u)
            + pf[2] * u2f(w4.y << 16) + pf[3] * u2f(w4.y & 0xFFFF0000u)
            + pf[4] * u2f(w4.z << 16) + pf[5] * u2f(w4.z & 0xFFFF0000u)
            + pf[6] * u2f(w4.w << 16) + pf[7] * u2f(w4.w & 0xFFFF0000u);
    }
    fs[768 + j] = fmaxf(acc2, 0.f);
  }
  __syncthreads();
  {
    float s = 0.f;
    for (int u = t; u < 1536; u += 256) { float v = fs[u]; s += v * v; }
#pragma unroll
    for (int off = 32; off > 0; off >>= 1) s += __shfl_xor(s, off);
    if (ln == 0) a4[wv] = s;
  }
  __syncthreads();
  float rnf = rsqrtf(a4[0] + a4[1] + a4[2] + a4[3]);
  {
    int lab = labels[b];
    const float cos_m = 0.8775825618903728f, sin_m = 0.479425538604203f;
    const float th = -0.8775825618903728f, mm = 0.2397127693021015f;
    for (int c = wv; c < CC; c += 4) {
      const float* wr = arc_w + (size_t)c * 1536;
      float acc = 0.f, nw = 0.f;
#pragma unroll
      for (int k = 0; k < 24; k++) {
        int d = ln + 64 * k;
        float a = fs[d], w = wr[d];
        acc += a * w; nw += w * w;
      }
#pragma unroll
      for (int off = 32; off > 0; off >>= 1) {
        acc += __shfl_xor(acc, off); nw += __shfl_xor(nw, off);
      }
      if (ln == 0) {
        float cosv = acc * rsqrtf(nw) * rnf;
        float s2 = 1.f - cosv * cosv;
        s2 = fminf(fmaxf(s2, 0.f), 1.f);
        float sinv = sqrtf(s2);
        float phi = cosv * cos_m - sinv * sin_m;
        phi = (cosv > th) ? phi : (cosv - mm);
        out[(size_t)b * CC + c] = ((c == lab) ? phi : cosv) * 30.f;
      }
    }
  }
}

extern "C" void kernel_launch(void* const* d_in, const int* in_sizes, int n_in,
                              void* d_out, int out_size, void* d_ws, size_t ws_size,
                              hipStream_t stream) {
  const float* hidden = (const float*)d_in[0];
  const float* attns  = (const float*)d_in[1];
  const int*   labels = (const int*)d_in[2];
  const float* ln1_g  = (const float*)d_in[3];
  const float* ln1_b  = (const float*)d_in[4];
  const float* w_in   = (const float*)d_in[5];
  const float* b_in   = (const float*)d_in[6];
  const float* w_out  = (const float*)d_in[7];
  const float* b_out  = (const float*)d_in[8];
  const float* ln2_g  = (const float*)d_in[9];
  const float* ln2_b  = (const float*)d_in[10];
  const float* w_pool = (const float*)d_in[11];
  const float* b_pool = (const float*)d_in[12];
  const float* ptemp  = (const float*)d_in[13];
  const float* w_mlp  = (const float*)d_in[14];
  const float* b_mlp  = (const float*)d_in[15];
  const float* arc_w  = (const float*)d_in[16];
  float* outp = (float*)d_out;

  float* F = (float*)d_ws;
  float* part_ws = F;                                          // 2359296 f32
  __hip_bfloat16* parts_bf = (__hip_bfloat16*)(F + 2359296);   // 589824 bf16
  __hip_bfloat16* w_in_bf  = (__hip_bfloat16*)(F + 2654208);   // 1769472 bf16
  __hip_bfloat16* w_out_bf = (__hip_bfloat16*)(F + 3538944);   // 589824 bf16
  __hip_bfloat16* w_mlp_bf = (__hip_bfloat16*)(F + 3833856);   // 589824 bf16

  k1_front<<<320, 256, 0, stream>>>(hidden, attns, ln1_g, ln1_b, w_in, w_out,
                                    w_mlp, w_in_bf, w_out_bf, w_mlp_bf, parts_bf);
  k2_mid<<<256, 256, 0, stream>>>(parts_bf, w_in_bf, b_in, w_out_bf, part_ws);
  k3_tail<<<BB, 256, 0, stream>>>(part_ws, b_out, ln2_g, ln2_b, w_pool, b_pool,
                                  ptemp, w_mlp_bf, b_mlp, hidden, arc_w, labels,
                                  outp);
}

// Round 12
// 120.007 us; speedup vs baseline: 2.4291x; 1.1993x over previous
//
#include <hip/hip_runtime.h>
#include <hip/hip_bf16.h>
#include <float.h>
#include <math.h>

#define BB 64
#define NNtok 197
#define DD 768
#define HH 12
#define PP 12
#define CC 200
#define NPATCH 196

typedef short bf16x8 __attribute__((ext_vector_type(8)));
typedef float f32x4 __attribute__((ext_vector_type(4)));

__device__ __forceinline__ unsigned short bf16_bits(float x) {
  __hip_bfloat16 h = __float2bfloat16(x);
  return *reinterpret_cast<unsigned short*>(&h);
}
__device__ __forceinline__ float u2f(unsigned int u) {
  union { unsigned int u; float f; } cv; cv.u = u; return cv.f;
}
__device__ __forceinline__ float bfu(unsigned short us) {
  union { unsigned int u; float f; } cv; cv.u = ((unsigned int)us) << 16; return cv.f;
}

// ================= K1: select+top12+LN1 (blk<64) | weight casts =============
__global__ __launch_bounds__(256) void k1_front(
    const float* __restrict__ hidden, const float* __restrict__ attns,
    const float* __restrict__ g, const float* __restrict__ be,
    const float* __restrict__ w1, const float* __restrict__ w2,
    const float* __restrict__ w3, __hip_bfloat16* __restrict__ o1,
    __hip_bfloat16* __restrict__ o2, __hip_bfloat16* __restrict__ o3,
    __hip_bfloat16* __restrict__ parts) {
  int t = threadIdx.x, bi = blockIdx.x;
  if (bi >= 64) {
    for (int i = (bi - 64) * 256 + t; i < 737280; i += 256 * 256) {
      const float* src; __hip_bfloat16* dst; int off;
      if (i < 442368) { src = w1; dst = o1; off = i; }
      else if (i < 589824) { src = w2; dst = o2; off = i - 442368; }
      else { src = w3; dst = o3; off = i - 589824; }
      float4 v = ((const float4*)src)[off];
      union { unsigned short u[4]; ushort4 v4; } p;
      p.u[0] = bf16_bits(v.x); p.u[1] = bf16_bits(v.y);
      p.u[2] = bf16_bits(v.z); p.u[3] = bf16_bits(v.w);
      ((ushort4*)dst)[off] = p.v4;
    }
    return;
  }
  int b = bi;
  __shared__ float sc[256];
  __shared__ int sel_s[PP];
  int wv = t >> 6, ln = t & 63;
  float acc = -FLT_MAX;
  if (t < NPATCH) {
    acc = 0.f;
#pragma unroll
    for (int l = 0; l < 4; l++) {
      float part = 0.f;
#pragma unroll
      for (int h = 0; h < HH; h++) {
        size_t base = (size_t)((l * BB + b) * HH + h) * ((size_t)NNtok * NNtok);
        part += attns[base + 1 + t];
      }
      acc += part * (1.f / 12.f);
    }
    acc *= 0.25f;
  }
  sc[t] = acc;
  __syncthreads();
  if (t < 64) {
    float v[4]; int idx[4];
#pragma unroll
    for (int j = 0; j < 4; j++) { idx[j] = t + j * 64; v[j] = sc[idx[j]]; }
    for (int it = 0; it < PP; ++it) {
      float bv = v[0]; int bidx = idx[0];
#pragma unroll
      for (int j = 1; j < 4; j++)
        if (v[j] > bv || (v[j] == bv && idx[j] < bidx)) { bv = v[j]; bidx = idx[j]; }
      float cv = bv; int ci = bidx;
#pragma unroll
      for (int off = 32; off > 0; off >>= 1) {
        float ov = __shfl_xor(cv, off); int oi = __shfl_xor(ci, off);
        if (ov > cv || (ov == cv && oi < ci)) { cv = ov; ci = oi; }
      }
      if (t == 0) sel_s[it] = ci;
#pragma unroll
      for (int j = 0; j < 4; j++)
        if (idx[j] == ci) v[j] = -FLT_MAX;
    }
  }
  __syncthreads();
#pragma unroll
  for (int q = 0; q < 3; q++) {
    int i = wv * 3 + q;
    const float* row = hidden + ((size_t)b * NNtok + 1 + sel_s[i]) * DD;
    float x[12], s1 = 0.f, s2 = 0.f;
#pragma unroll
    for (int k = 0; k < 12; k++) {
      x[k] = row[ln + 64 * k];
      s1 += x[k]; s2 += x[k] * x[k];
    }
#pragma unroll
    for (int off = 32; off > 0; off >>= 1) {
      s1 += __shfl_xor(s1, off); s2 += __shfl_xor(s2, off);
    }
    float m = s1 * (1.f / DD);
    float rstd = rsqrtf(s2 * (1.f / DD) - m * m + 1e-5f);
    __hip_bfloat16* outp_ = parts + ((size_t)b * PP + i) * DD;
#pragma unroll
    for (int k = 0; k < 12; k++) {
      int d = ln + 64 * k;
      outp_[d] = __float2bfloat16((x[k] - m) * rstd * g[d] + be[d]);
    }
  }
}

// ====== K2: per (b,hg): qkv-slice GEMM + 3-head attention + partial wout ====
__global__ __launch_bounds__(256) void k2_mid(
    const __hip_bfloat16* __restrict__ parts, const __hip_bfloat16* __restrict__ w_in_bf,
    const float* __restrict__ b_in, const __hip_bfloat16* __restrict__ w_out_bf,
    float* __restrict__ part_ws) {
  int bi = blockIdx.x;
  int b = bi >> 2, hg = bi & 3;  // hg = XCD&3 under round-robin: slice L2-pinned
  int t = threadIdx.x;
  int wave = t >> 6, lane = t & 63, lr = lane & 15, kg = lane >> 4;
  __shared__ __align__(16) unsigned short qkv3[3][16][192];
  __shared__ __align__(16) unsigned short o3[16][192];
  __shared__ float scores[432];

  int pr = lr < 12 ? lr : 11;
  const __hip_bfloat16* Ab = parts + ((size_t)b * 12 + pr) * DD + kg * 8;
  int wrow[9];
#pragma unroll
  for (int nf = 0; nf < 9; nf++) {
    int lc = wave * 144 + nf * 16 + lr;
    int s = lc / 192, d2 = lc - s * 192;
    wrow[nf] = s * 768 + hg * 192 + d2;
  }
  f32x4 acc[9];
#pragma unroll
  for (int nf = 0; nf < 9; nf++) { acc[nf][0]=0.f; acc[nf][1]=0.f; acc[nf][2]=0.f; acc[nf][3]=0.f; }
  for (int k0 = 0; k0 < 768; k0 += 32) {
    bf16x8 af = *(const bf16x8*)(Ab + k0);
    bf16x8 wf[9];
#pragma unroll
    for (int nf = 0; nf < 9; nf++)
      wf[nf] = *(const bf16x8*)(w_in_bf + (size_t)wrow[nf] * DD + kg * 8 + k0);
#pragma unroll
    for (int nf = 0; nf < 9; nf++)
      acc[nf] = __builtin_amdgcn_mfma_f32_16x16x32_bf16(af, wf[nf], acc[nf], 0, 0, 0);
  }
#pragma unroll
  for (int nf = 0; nf < 9; nf++) {
    int lc = wave * 144 + nf * 16 + lr;
    int s = lc / 192, d2 = lc - s * 192;
    float bv = b_in[s * 768 + hg * 192 + d2];
#pragma unroll
    for (int r = 0; r < 4; r++) {
      int p = kg * 4 + r;
      qkv3[s][p][d2] = bf16_bits(acc[nf][r] + bv);
    }
  }
  __syncthreads();

  for (int e = t; e < 432; e += 256) {
    int h = e / 144, rem = e - h * 144;
    int i = rem / 12, j = rem - i * 12;
    float s = 0.f;
#pragma unroll
    for (int d = 0; d < 64; d++)
      s += bfu(qkv3[0][i][h * 64 + d]) * bfu(qkv3[1][j][h * 64 + d]);
    scores[e] = s * 0.125f;
  }
  __syncthreads();
  if (t < 36) {
    int h = t / 12, i = t - h * 12;
    float* row = scores + h * 144 + i * 12;
    float m = -FLT_MAX;
#pragma unroll
    for (int j = 0; j < 12; j++) m = fmaxf(m, row[j]);
    float e2[12], sum = 0.f;
#pragma unroll
    for (int j = 0; j < 12; j++) { e2[j] = expf(row[j] - m); sum += e2[j]; }
    float inv = 1.f / sum;
#pragma unroll
    for (int j = 0; j < 12; j++) row[j] = e2[j] * inv;
  }
  __syncthreads();
  for (int o = t; o < 2304; o += 256) {
    int i = o / 192, d2 = o - i * 192;
    int h = d2 >> 6;
    float s = 0.f;
#pragma unroll
    for (int j = 0; j < 12; j++)
      s += scores[h * 144 + i * 12 + j] * bfu(qkv3[2][j][d2]);
    o3[i][d2] = bf16_bits(s);
  }
  __syncthreads();

  f32x4 acc2[12];
#pragma unroll
  for (int jf = 0; jf < 12; jf++) { acc2[jf][0]=0.f; acc2[jf][1]=0.f; acc2[jf][2]=0.f; acc2[jf][3]=0.f; }
  const unsigned short* Ob = &o3[0][0] + lr * 192 + kg * 8;
  for (int k0 = 0; k0 < 192; k0 += 32) {
    bf16x8 af = *(const bf16x8*)(Ob + k0);
    bf16x8 wf[12];
#pragma unroll
    for (int jf = 0; jf < 12; jf++) {
      int j = wave * 192 + jf * 16 + lr;
      wf[jf] = *(const bf16x8*)(w_out_bf + (size_t)j * DD + hg * 192 + kg * 8 + k0);
    }
#pragma unroll
    for (int jf = 0; jf < 12; jf++)
      acc2[jf] = __builtin_amdgcn_mfma_f32_16x16x32_bf16(af, wf[jf], acc2[jf], 0, 0, 0);
  }
#pragma unroll
  for (int jf = 0; jf < 12; jf++) {
    int j = wave * 192 + jf * 16 + lr;
#pragma unroll
    for (int r = 0; r < 4; r++) {
      int p = kg * 4 + r;
      if (p < 12)
        part_ws[(((size_t)b * 4 + hg) * 12 + p) * DD + j] = acc2[jf][r];
    }
  }
}

// == K3 (256 blocks, (b,q4)): reduce + LN2 + pool + full MLP + ArcFace(50) ===
__global__ __launch_bounds__(256) void k3_tail(
    const float* __restrict__ part_ws, const float* __restrict__ b_out,
    const float* __restrict__ g, const float* __restrict__ be,
    const float* __restrict__ wp, const float* __restrict__ bp,
    const float* __restrict__ ptemp, const __hip_bfloat16* __restrict__ wmlp,
    const float* __restrict__ bmlp, const float* __restrict__ hidden,
    const float* __restrict__ arc_w, const int* __restrict__ labels,
    float* __restrict__ out) {
  int bi = blockIdx.x;
  int b = bi >> 2, q4 = bi & 3;  // q4 = XCD&3: arc_w quarter L2-pinned
  int t = threadIdx.x, wv = t >> 6, ln = t & 63;
  __shared__ __align__(16) float aout[12 * 768];
  __shared__ float pfeat[768];
  __shared__ __align__(16) float fs[1536];
  __shared__ float raww[12];
  __shared__ float a4[4];
  for (int u = t; u < 9216; u += 256) {
    int j = u % 768;
    float s = b_out[j];
#pragma unroll
    for (int g4 = 0; g4 < 4; g4++)
      s += part_ws[(((size_t)b * 4 + g4) * 12) * DD + u];
    aout[u] = s;
  }
  __syncthreads();
#pragma unroll
  for (int q = 0; q < 3; q++) {
    int r = wv * 3 + q;
    float x[12], s1 = 0.f, s2 = 0.f;
#pragma unroll
    for (int k = 0; k < 12; k++) {
      x[k] = aout[r * DD + ln + 64 * k];
      s1 += x[k]; s2 += x[k] * x[k];
    }
#pragma unroll
    for (int off = 32; off > 0; off >>= 1) {
      s1 += __shfl_xor(s1, off); s2 += __shfl_xor(s2, off);
    }
    float m = s1 * (1.f / DD);
    float rstd = rsqrtf(s2 * (1.f / DD) - m * m + 1e-5f);
    float pl = 0.f;
#pragma unroll
    for (int k = 0; k < 12; k++) {
      int d = ln + 64 * k;
      float y = (x[k] - m) * rstd * g[d] + be[d];
      aout[r * DD + d] = y;
      pl += y * wp[d];
    }
#pragma unroll
    for (int off = 32; off > 0; off >>= 1) pl += __shfl_xor(pl, off);
    if (ln == 0) raww[r] = pl + bp[0];
  }
  __syncthreads();
  {
    float wts[12];
    float inv = 1.f / fmaxf(ptemp[0], 0.3f);
    float z[12], mx = -FLT_MAX;
#pragma unroll
    for (int p = 0; p < 12; p++) { z[p] = raww[p] * inv; mx = fmaxf(mx, z[p]); }
    float sme = 0.f;
#pragma unroll
    for (int p = 0; p < 12; p++) { z[p] = expf(z[p] - mx); sme += z[p]; }
    float is = 1.f / sme;
#pragma unroll
    for (int p = 0; p < 12; p++) wts[p] = z[p] * is;
    for (int d = t; d < 768; d += 256) {
      float s = 0.f;
#pragma unroll
      for (int p = 0; p < 12; p++) s += aout[p * DD + d] * wts[p];
      pfeat[d] = s;
      fs[d] = hidden[(size_t)b * NNtok * DD + d];  // cls token
    }
  }
  __syncthreads();
  // full MLP GEMV (redundant per q4; weights L2-resident)
#pragma unroll
  for (int r3 = 0; r3 < 3; r3++) {
    int j = t + 256 * r3;
    const uint4* wr = (const uint4*)(wmlp + (size_t)j * DD);
    float acc2 = bmlp[j];
    for (int k = 0; k < 96; k++) {
      uint4 w4 = wr[k];
      const float* pf = &pfeat[k * 8];
      acc2 += pf[0] * u2f(w4.x << 16) + pf[1] * u2f(w4.x & 0xFFFF0000u)
            + pf[2] * u2f(w4.y << 16) + pf[3] * u2f(w4.y & 0xFFFF0000u)
            + pf[4] * u2f(w4.z << 16) + pf[5] * u2f(w4.z & 0xFFFF0000u)
            + pf[6] * u2f(w4.w << 16) + pf[7] * u2f(w4.w & 0xFFFF0000u);
    }
    fs[768 + j] = fmaxf(acc2, 0.f);
  }
  __syncthreads();
  {
    float s = 0.f;
    for (int u = t; u < 1536; u += 256) { float v = fs[u]; s += v * v; }
#pragma unroll
    for (int off = 32; off > 0; off >>= 1) s += __shfl_xor(s, off);
    if (ln == 0) a4[wv] = s;
  }
  __syncthreads();
  float rnf = rsqrtf(a4[0] + a4[1] + a4[2] + a4[3]);
  {
    int lab = labels[b];
    const float cos_m = 0.8775825618903728f, sin_m = 0.479425538604203f;
    const float th = -0.8775825618903728f, mm = 0.2397127693021015f;
    int c0 = q4 * 50;
    for (int c = c0 + wv; c < c0 + 50; c += 4) {
      const float* wr = arc_w + (size_t)c * 1536;
      float acc = 0.f, nw = 0.f;
#pragma unroll
      for (int k = 0; k < 24; k++) {
        int d = ln + 64 * k;
        float a = fs[d], w = wr[d];
        acc += a * w; nw += w * w;
      }
#pragma unroll
      for (int off = 32; off > 0; off >>= 1) {
        acc += __shfl_xor(acc, off); nw += __shfl_xor(nw, off);
      }
      if (ln == 0) {
        float cosv = acc * rsqrtf(nw) * rnf;
        float s2 = 1.f - cosv * cosv;
        s2 = fminf(fmaxf(s2, 0.f), 1.f);
        float sinv = sqrtf(s2);
        float phi = cosv * cos_m - sinv * sin_m;
        phi = (cosv > th) ? phi : (cosv - mm);
        out[(size_t)b * CC + c] = ((c == lab) ? phi : cosv) * 30.f;
      }
    }
  }
}

extern "C" void kernel_launch(void* const* d_in, const int* in_sizes, int n_in,
                              void* d_out, int out_size, void* d_ws, size_t ws_size,
                              hipStream_t stream) {
  const float* hidden = (const float*)d_in[0];
  const float* attns  = (const float*)d_in[1];
  const int*   labels = (const int*)d_in[2];
  const float* ln1_g  = (const float*)d_in[3];
  const float* ln1_b  = (const float*)d_in[4];
  const float* w_in   = (const float*)d_in[5];
  const float* b_in   = (const float*)d_in[6];
  const float* w_out  = (const float*)d_in[7];
  const float* b_out  = (const float*)d_in[8];
  const float* ln2_g  = (const float*)d_in[9];
  const float* ln2_b  = (const float*)d_in[10];
  const float* w_pool = (const float*)d_in[11];
  const float* b_pool = (const float*)d_in[12];
  const float* ptemp  = (const float*)d_in[13];
  const float* w_mlp  = (const float*)d_in[14];
  const float* b_mlp  = (const float*)d_in[15];
  const float* arc_w  = (const float*)d_in[16];
  float* outp = (float*)d_out;

  float* F = (float*)d_ws;
  float* part_ws = F;                                          // 2359296 f32
  __hip_bfloat16* parts_bf = (__hip_bfloat16*)(F + 2359296);   // 589824 bf16
  __hip_bfloat16* w_in_bf  = (__hip_bfloat16*)(F + 2654208);   // 1769472 bf16
  __hip_bfloat16* w_out_bf = (__hip_bfloat16*)(F + 3538944);   // 589824 bf16
  __hip_bfloat16* w_mlp_bf = (__hip_bfloat16*)(F + 3833856);   // 589824 bf16

  k1_front<<<320, 256, 0, stream>>>(hidden, attns, ln1_g, ln1_b, w_in, w_out,
                                    w_mlp, w_in_bf, w_out_bf, w_mlp_bf, parts_bf);
  k2_mid<<<256, 256, 0, stream>>>(parts_bf, w_in_bf, b_in, w_out_bf, part_ws);
  k3_tail<<<256, 256, 0, stream>>>(part_ws, b_out, ln2_g, ln2_b, w_pool, b_pool,
                                   ptemp, w_mlp_bf, b_mlp, hidden, arc_w, labels,
                                   outp);
}